// Round 14
// baseline (140.307 us; speedup 1.0000x reference)
//
#include <hip/hip_runtime.h>
#include <hip/hip_bf16.h>

typedef __bf16 bf16x8 __attribute__((ext_vector_type(8)));
typedef float  f32x4  __attribute__((ext_vector_type(4)));
typedef float  f4     __attribute__((ext_vector_type(4)));
typedef unsigned short us4 __attribute__((ext_vector_type(4)));
typedef unsigned short us8 __attribute__((ext_vector_type(8)));

__device__ inline unsigned short f2bf(float f) {
  union { float f; unsigned int u; } v; v.f = f;
  unsigned int r = v.u + 0x7fffu + ((v.u >> 16) & 1u);
  return (unsigned short)(r >> 16);
}

__device__ inline void gload_lds16(const void* g, void* l) {
  __builtin_amdgcn_global_load_lds((const __attribute__((address_space(1))) void*)g,
                                   (__attribute__((address_space(3))) void*)l, 16, 0, 0);
}

// ------- fused: fp32->bf16 convert of x  +  W transpose/concat to bf16 -------
__global__ __launch_bounds__(256) void convfused(const float* __restrict__ x,
                                                 const float* __restrict__ Wq,
                                                 const float* __restrict__ Wk,
                                                 const float* __restrict__ Wv,
                                                 unsigned short* __restrict__ xb,
                                                 unsigned short* __restrict__ wt) {
  __shared__ unsigned short tile[32][33];
  if (blockIdx.x < 3072) {
    int i = blockIdx.x * 256 + threadIdx.x;       // indexes float4
    f4 v = ((const f4*)x)[i];
    us4 o;
    #pragma unroll
    for (int c = 0; c < 4; ++c) o[c] = f2bf(v[c]);
    ((us4*)xb)[i] = o;
  } else {
    int b = blockIdx.x - 3072;                    // 0..1727 = 3 * 24 * 24
    int bz = b / 576, rem = b % 576;
    int bx = rem / 24, by = rem % 24;
    const float* W = bz == 0 ? Wq : (bz == 1 ? Wk : Wv);
    int k0 = bx * 32, n0 = by * 32;
    int c = threadIdx.x & 31, r8 = threadIdx.x >> 5;
    #pragma unroll
    for (int p = 0; p < 4; ++p) {
      int r = p * 8 + r8;
      tile[r][c] = f2bf(W[(size_t)(k0 + r) * 768 + n0 + c]);
    }
    __syncthreads();
    #pragma unroll
    for (int p = 0; p < 4; ++p) {
      int r = p * 8 + r8;  // n index
      wt[((size_t)bz * 768 + n0 + r) * 768 + k0 + c] = tile[c][r];
    }
  }
}

// ======== deep-pipelined bf16 GEMM: ring-4 K32 slots + register read-ahead ========
// (round-8 proven core: 16x16x32 MFMA, counted vmcnt, reg ping-pong, st_16x32 swizzle)
// Step s: vmcnt(4) -> barrier -> stage slot (s+3)&3 -> prefetch frags of slot (s+1)&3
// into the alternate named register set (rule #20) -> MFMA on current set.
// Hazards: stage(s) writes slot (s-1)&3, last read at step s-2 (lgkmcnt'd before
// MFMA(s-1), ordered by step-s barrier). vmcnt(4) forces slot s+1 landed. nsteps even.
// LDS swizzle: byte ^ ((row_bit3)<<5); staging pre-swizzles the GLOBAL source k.
// DOEXP: epilogue v = exp(v*cscale). DOSCALE: epilogue v *= rowinv[r].
// PSUM: per-wave-block row sums of exp -> psum[cg][r], cg = bx*WN + wc.
//   (4-wave only: the 8-wave kernel is 256-VGPR-capped and spills — round 11/12.)
// UNI: unified two-geometry dispatch — blocks with swz < nsplit use geometry 1
//   (A,B,C0,lda,ldb,ldc,nbx), the rest use geometry 2 (A2,B2,C2,lda2,ldb2,ldc2,nbx2).
// Split-K (non-UNI): gridDim.y slice y computes K [y*kspan,(y+1)*kspan) -> C0/C1.
template <int WAVES, int WM, int WN, int MINW, typename OUT_T,
          bool DOEXP, bool DOSCALE, bool UNI, bool PSUM>
__global__ __launch_bounds__(WAVES * 64, MINW) void gemmdp(const unsigned short* __restrict__ A,
                                                           const unsigned short* __restrict__ B,
                                                           OUT_T* __restrict__ C0,
                                                           OUT_T* __restrict__ C1,
                                                           const float* __restrict__ rowinv,
                                                           float* __restrict__ psum,
                                                           const unsigned short* __restrict__ A2,
                                                           const unsigned short* __restrict__ B2,
                                                           OUT_T* __restrict__ C2,
                                                           int lda, int ldb, int ldc, int nbx,
                                                           int lda2, int ldb2, int ldc2, int nbx2,
                                                           int nsplit, int kspan, float cscale) {
  constexpr int BM = WAVES * 32, BN = WAVES * 32;
  constexpr int MF = 2 * WAVES / WM, NF = 2 * WAVES / WN;
  constexpr int SLOT = (BM + BN) * 64;
  __shared__ __align__(16) char lds[4 * SLOT];
  const int tid = threadIdx.x;
  const int w = tid >> 6, l = tid & 63;
  const int wr = w / WN, wc = w % WN;
  const int lr = l & 15, lk = l >> 4;

  const int nwg = gridDim.x;             // bijective XCD swizzle (nwg % 8 == 0)
  const int swz = (blockIdx.x & 7) * (nwg >> 3) + (blockIdx.x >> 3);

  // ---- geometry routing (block-uniform) ----
  const unsigned short* Ap = A;
  const unsigned short* Bp = B;
  OUT_T* Cp = blockIdx.y ? C1 : C0;
  int LDA = lda, LDB = ldb, LDC = ldc;
  int bx, by;
  if constexpr (UNI) {
    if (swz < nsplit) { bx = swz % nbx;  by = swz / nbx; }
    else {
      int s2 = swz - nsplit;
      bx = s2 % nbx2; by = s2 / nbx2;
      Ap = A2; Bp = B2; Cp = C2; LDA = lda2; LDB = ldb2; LDC = ldc2;
    }
  } else {
    bx = swz % nbx; by = swz / nbx;
  }
  const int m0 = by * BM, n0 = bx * BN;
  const int koff0 = blockIdx.y * kspan;

  f32x4 acc[MF][NF] = {};

  // --- staging: thread covers 4x 16B chunks (A rows trow, trow+BM/2; B same) ---
  const int trow = tid >> 2;
  const int koff = ((tid & 3) * 8) ^ (((tid >> 5) & 1) * 16);  // inverse-swizzled source k
  const unsigned short* gA0 = Ap + (size_t)(m0 + trow) * LDA + koff + koff0;
  const unsigned short* gA1 = Ap + (size_t)(m0 + BM / 2 + trow) * LDA + koff + koff0;
  const unsigned short* gB0 = Bp + (size_t)(n0 + trow) * LDB + koff + koff0;
  const unsigned short* gB1 = Bp + (size_t)(n0 + BN / 2 + trow) * LDB + koff + koff0;
  const int wave16 = (tid & ~63) * 16;   // wave-uniform LDS chunk base

  auto stage = [&](int slot, int k0) {
    char* base = lds + slot * SLOT;
    gload_lds16(gA0 + k0, base + wave16);
    gload_lds16(gA1 + k0, base + BM * 32 + wave16);
    gload_lds16(gB0 + k0, base + BM * 64 + wave16);
    gload_lds16(gB1 + k0, base + BM * 64 + BN * 32 + wave16);
  };

  // --- fragment read offsets (within slot); xor bit5 by row bit3 ---
  const int xorv = ((l >> 3) & 1) << 5;
  const int aoff = (wr * (MF * 16) + lr) * 64 + lk * 16;            // + mf*1024
  const int boff = BM * 64 + (wc * (NF * 16) + lr) * 64 + lk * 16;  // + nf*1024

  auto ldfrags = [&](int slot, bf16x8 (&pa)[MF], bf16x8 (&pb)[NF]) {
    const char* sb = lds + slot * SLOT;
    #pragma unroll
    for (int mf = 0; mf < MF; ++mf)
      pa[mf] = *(const bf16x8*)(sb + ((aoff + mf * 1024) ^ xorv));
    #pragma unroll
    for (int nf = 0; nf < NF; ++nf)
      pb[nf] = *(const bf16x8*)(sb + ((boff + nf * 1024) ^ xorv));
  };

  const int nsteps = kspan >> 5;         // even by construction
  bf16x8 fa[MF], fb[NF], ga[MF], gb[NF];

  stage(0, 0); stage(1, 32); stage(2, 64);
  asm volatile("s_waitcnt vmcnt(8)" ::: "memory");   // slot 0 landed (own wave)
  __builtin_amdgcn_s_barrier();                      // slot 0 landed (all waves)
  ldfrags(0, fa, fb);                                // prefetch step-0 frags

  auto step = [&](int s, bf16x8 (&ca)[MF], bf16x8 (&cb)[NF],
                  bf16x8 (&xa)[MF], bf16x8 (&xb2)[NF]) {
    __builtin_amdgcn_sched_barrier(0);
    if (s < nsteps - 2) asm volatile("s_waitcnt vmcnt(4)" ::: "memory");
    else                asm volatile("s_waitcnt vmcnt(0)" ::: "memory");
    __builtin_amdgcn_s_barrier();
    __builtin_amdgcn_sched_barrier(0);

    if (s + 3 < nsteps) stage((s + 3) & 3, (s + 3) << 5);  // slot (s-1)&3, read done @s-2
    if (s + 1 < nsteps) ldfrags((s + 1) & 3, xa, xb2);     // prefetch next step's frags

    __builtin_amdgcn_s_setprio(1);
    #pragma unroll
    for (int mf = 0; mf < MF; ++mf)
      #pragma unroll
      for (int nf = 0; nf < NF; ++nf)
        acc[mf][nf] = __builtin_amdgcn_mfma_f32_16x16x32_bf16(ca[mf], cb[nf], acc[mf][nf], 0, 0, 0);
    __builtin_amdgcn_s_setprio(0);
  };

  for (int s = 0; s < nsteps; s += 2) {
    step(s,     fa, fb, ga, gb);   // consume fa/fb, prefetch into ga/gb
    step(s + 1, ga, gb, fa, fb);   // consume ga/gb, prefetch into fa/fb
  }

  // ---------------- epilogue ----------------
  if constexpr (DOEXP) {
    #pragma unroll
    for (int mf = 0; mf < MF; ++mf)
      #pragma unroll
      for (int nf = 0; nf < NF; ++nf)
        #pragma unroll
        for (int i = 0; i < 4; ++i)
          acc[mf][nf][i] = __expf(acc[mf][nf][i] * cscale);
  }

  #pragma unroll
  for (int mf = 0; mf < MF; ++mf)
    #pragma unroll
    for (int nf = 0; nf < NF; ++nf)
      #pragma unroll
      for (int i = 0; i < 4; ++i) {
        int r = m0 + wr * (MF * 16) + mf * 16 + lk * 4 + i;
        int c = n0 + wc * (NF * 16) + nf * 16 + lr;
        float v = acc[mf][nf][i];
        if constexpr (!DOEXP) v *= cscale;
        if constexpr (DOSCALE) v *= rowinv[r];
        if constexpr (__is_same(OUT_T, unsigned short)) Cp[(size_t)r * LDC + c] = f2bf(v);
        else                                            Cp[(size_t)r * LDC + c] = v;
      }

  if constexpr (PSUM) {
    // per-wave-block row sums of exp (NF*16 = 64 columns): reduce nf, then lr-group
    const int cg = bx * WN + wc;         // column group 0..63
    #pragma unroll
    for (int mf = 0; mf < MF; ++mf)
      #pragma unroll
      for (int i = 0; i < 4; ++i) {
        float rp = 0.f;
        #pragma unroll
        for (int nf = 0; nf < NF; ++nf) rp += acc[mf][nf][i];
        rp += __shfl_xor(rp, 1);
        rp += __shfl_xor(rp, 2);
        rp += __shfl_xor(rp, 4);
        rp += __shfl_xor(rp, 8);         // sum over the 16-lane lr group
        if (lr == 0) {
          int r = m0 + wr * (MF * 16) + mf * 16 + lk * 4 + i;
          psum[(size_t)cg * 4096 + r] = rp;
        }
      }
  }
}

// ------- rowinv[r] = 1 / sum_cg psum[cg][r] -------
__global__ __launch_bounds__(256) void rowinvk(const float* __restrict__ psum,
                                               float* __restrict__ rowinv) {
  int r = blockIdx.x * 256 + threadIdx.x;   // grid 16
  float s = 0.f;
  #pragma unroll
  for (int cg = 0; cg < 64; ++cg) s += psum[(size_t)cg * 4096 + r];
  rowinv[r] = 1.f / s;
}

// ------- out += p1 (f4 elementwise) -------
__global__ __launch_bounds__(256) void reduce_add(float* __restrict__ out,
                                                  const float* __restrict__ p1) {
  int i = blockIdx.x * 256 + threadIdx.x;
  f4 a = ((const f4*)out)[i];
  f4 b = ((const f4*)p1)[i];
  #pragma unroll
  for (int c = 0; c < 4; ++c) a[c] += b[c];
  ((f4*)out)[i] = a;
}

extern "C" void kernel_launch(void* const* d_in, const int* in_sizes, int n_in,
                              void* d_out, int out_size, void* d_ws, size_t ws_size,
                              hipStream_t stream) {
  const float* x  = (const float*)d_in[0];
  const float* Wq = (const float*)d_in[1];
  const float* Wk = (const float*)d_in[2];
  const float* Wv = (const float*)d_in[3];
  float* out = (float*)d_out;
  char* ws = (char*)d_ws;

  // ws layout (bytes):
  //   [0, 12582912)            qkv bf16 [4096][1536] (Q|K); dead after QK gemm ->
  //                            reused as PV split-K partial p1 fp32 [4096][768]
  //   [18874368, 52428800)     P bf16 [4096][4096] (unnormalized exp(scores))
  //       xb (6.3MB) and wt (3.5MB) alias this region; both dead before QK writes P
  //   [52428800, 58720256)     Vt bf16 [768][4096] (written directly by unified gemm)
  //   [58720256, 58736640)     rowinv fp32 [4096]
  //   [58736640, 59785216)     psum fp32 [64][4096]
  unsigned short* qkv = (unsigned short*)ws;
  unsigned short* P   = (unsigned short*)(ws + 18874368);
  unsigned short* xb  = (unsigned short*)(ws + 18874368);
  unsigned short* wt  = (unsigned short*)(ws + 18874368 + 6291456);
  unsigned short* vt  = (unsigned short*)(ws + 52428800);
  float* rowinvp      = (float*)(ws + 58720256);
  float* psum         = (float*)(ws + 58736640);
  float* p1           = (float*)ws;                    // aliases qkv (dead by then)

  const float qscale = 0.03608439182435161f;  // 1/sqrt(768)

  convfused<<<4800, 256, 0, stream>>>(x, Wq, Wk, Wv, xb, wt);
  // Unified projection dispatch (576 blocks, ring-4+RA, K=768):
  //   blocks [0,384):  QK-part  = x @ [Wq|Wk]  -> qkv [4096][1536]
  //   blocks [384,576): VT-part = Wv^T @ x^T   -> vt  [768][4096]
  gemmdp<4, 2, 2, 2, unsigned short, false, false, true, false><<<576, 256, 0, stream>>>(
      xb, wt, qkv, qkv, nullptr, nullptr,
      wt + (size_t)1536 * 768, xb, vt,
      768, 768, 1536, 12,
      768, 768, 4096, 32,
      384, 768, 1.0f);
  // P = exp((Q @ K^T) * qscale)  (M=4096, N=4096, K=768), 128x128 -> 1024 blocks
  //   (4-wave, 64KB LDS -> 2 blocks/CU: cross-block overlap hides per-step sync);
  //   per-wave-block row partials of exp -> psum (no rowsum pass)
  gemmdp<4, 2, 2, 2, unsigned short, true, false, false, true><<<1024, 256, 0, stream>>>(
      qkv, qkv + 768, P, P, nullptr, psum, nullptr, nullptr, nullptr,
      1536, 1536, 4096, 32, 0, 0, 0, 0, 0, 768, qscale);
  // rowinv = 1 / row-sums (from psum, 1MB)
  rowinvk<<<16, 256, 0, stream>>>(psum, rowinvp);
  // out = (P @ V) * rowinv (M=4096, N=768, K=4096), 128x128, split-K=2, ring-4+RA
  gemmdp<4, 2, 2, 2, float, false, true, false, false><<<dim3(192, 2), 256, 0, stream>>>(
      P, vt, out, p1, rowinvp, nullptr, nullptr, nullptr, nullptr,
      4096, 4096, 768, 6, 0, 0, 0, 0, 0, 2048, 1.0f);
  reduce_add<<<3072, 256, 0, stream>>>(out, p1);
}

// Round 15
// 114.497 us; speedup vs baseline: 1.2254x; 1.2254x over previous
//
#include <hip/hip_runtime.h>
#include <hip/hip_bf16.h>

typedef __bf16 bf16x8 __attribute__((ext_vector_type(8)));
typedef float  f32x4  __attribute__((ext_vector_type(4)));
typedef float  f4     __attribute__((ext_vector_type(4)));
typedef unsigned short us4 __attribute__((ext_vector_type(4)));
typedef unsigned short us8 __attribute__((ext_vector_type(8)));

__device__ inline unsigned short f2bf(float f) {
  union { float f; unsigned int u; } v; v.f = f;
  unsigned int r = v.u + 0x7fffu + ((v.u >> 16) & 1u);
  return (unsigned short)(r >> 16);
}
__device__ inline float bf2f(unsigned short u) {
  union { unsigned int u; float f; } v; v.u = (unsigned int)u << 16;
  return v.f;
}

__device__ inline void gload_lds16(const void* g, void* l) {
  __builtin_amdgcn_global_load_lds((const __attribute__((address_space(1))) void*)g,
                                   (__attribute__((address_space(3))) void*)l, 16, 0, 0);
}

// ------- fused: fp32->bf16 convert of x  +  W transpose/concat to bf16 -------
__global__ __launch_bounds__(256) void convfused(const float* __restrict__ x,
                                                 const float* __restrict__ Wq,
                                                 const float* __restrict__ Wk,
                                                 const float* __restrict__ Wv,
                                                 unsigned short* __restrict__ xb,
                                                 unsigned short* __restrict__ wt) {
  __shared__ unsigned short tile[32][33];
  if (blockIdx.x < 3072) {
    int i = blockIdx.x * 256 + threadIdx.x;       // indexes float4
    f4 v = ((const f4*)x)[i];
    us4 o;
    #pragma unroll
    for (int c = 0; c < 4; ++c) o[c] = f2bf(v[c]);
    ((us4*)xb)[i] = o;
  } else {
    int b = blockIdx.x - 3072;                    // 0..1727 = 3 * 24 * 24
    int bz = b / 576, rem = b % 576;
    int bx = rem / 24, by = rem % 24;
    const float* W = bz == 0 ? Wq : (bz == 1 ? Wk : Wv);
    int k0 = bx * 32, n0 = by * 32;
    int c = threadIdx.x & 31, r8 = threadIdx.x >> 5;
    #pragma unroll
    for (int p = 0; p < 4; ++p) {
      int r = p * 8 + r8;
      tile[r][c] = f2bf(W[(size_t)(k0 + r) * 768 + n0 + c]);
    }
    __syncthreads();
    #pragma unroll
    for (int p = 0; p < 4; ++p) {
      int r = p * 8 + r8;  // n index
      wt[((size_t)bz * 768 + n0 + r) * 768 + k0 + c] = tile[c][r];
    }
  }
}

// ======== deep-pipelined bf16 GEMM: ring-4 K32 slots + register read-ahead ========
// (round-8 proven core: 16x16x32 MFMA, counted vmcnt, reg ping-pong, st_16x32 swizzle)
// Step s: vmcnt(4) -> barrier -> stage slot (s+3)&3 -> prefetch frags of slot (s+1)&3
// into the alternate named register set (rule #20) -> MFMA on current set.
// Hazards: stage(s) writes slot (s-1)&3, last read at step s-2 (lgkmcnt'd before
// MFMA(s-1), ordered by step-s barrier). vmcnt(4) forces slot s+1 landed. nsteps even.
// LDS swizzle: byte ^ ((row_bit3)<<5); staging pre-swizzles the GLOBAL source k.
// DOEXP: epilogue v = exp(v*cscale). DOSCALE: epilogue v *= rowinv[r].
// UNI: unified two-geometry dispatch — blocks with swz < nsplit use geometry 1
//   (A,B,C0,lda,ldb,ldc,nbx), the rest use geometry 2 (A2,B2,C2,lda2,ldb2,ldc2,nbx2).
//   All routing is block-uniform scalar math. gridDim.y == 1 for UNI.
// Split-K (non-UNI): gridDim.y slice y computes K [y*kspan,(y+1)*kspan) -> C0/C1.
template <int WAVES, int WM, int WN, int MINW, typename OUT_T, bool DOEXP, bool DOSCALE, bool UNI>
__global__ __launch_bounds__(WAVES * 64, MINW) void gemmdp(const unsigned short* __restrict__ A,
                                                           const unsigned short* __restrict__ B,
                                                           OUT_T* __restrict__ C0,
                                                           OUT_T* __restrict__ C1,
                                                           const float* __restrict__ rowinv,
                                                           const unsigned short* __restrict__ A2,
                                                           const unsigned short* __restrict__ B2,
                                                           OUT_T* __restrict__ C2,
                                                           int lda, int ldb, int ldc, int nbx,
                                                           int lda2, int ldb2, int ldc2, int nbx2,
                                                           int nsplit, int kspan, float cscale) {
  constexpr int BM = WAVES * 32, BN = WAVES * 32;
  constexpr int MF = 2 * WAVES / WM, NF = 2 * WAVES / WN;
  constexpr int SLOT = (BM + BN) * 64;
  __shared__ __align__(16) char lds[4 * SLOT];
  const int tid = threadIdx.x;
  const int w = tid >> 6, l = tid & 63;
  const int wr = w / WN, wc = w % WN;
  const int lr = l & 15, lk = l >> 4;

  const int nwg = gridDim.x;             // bijective XCD swizzle (nwg % 8 == 0)
  const int swz = (blockIdx.x & 7) * (nwg >> 3) + (blockIdx.x >> 3);

  // ---- geometry routing (block-uniform) ----
  const unsigned short* Ap = A;
  const unsigned short* Bp = B;
  OUT_T* Cp = blockIdx.y ? C1 : C0;
  int LDA = lda, LDB = ldb, LDC = ldc;
  int bx, by;
  if constexpr (UNI) {
    if (swz < nsplit) { bx = swz % nbx;  by = swz / nbx; }
    else {
      int s2 = swz - nsplit;
      bx = s2 % nbx2; by = s2 / nbx2;
      Ap = A2; Bp = B2; Cp = C2; LDA = lda2; LDB = ldb2; LDC = ldc2;
    }
  } else {
    bx = swz % nbx; by = swz / nbx;
  }
  const int m0 = by * BM, n0 = bx * BN;
  const int koff0 = blockIdx.y * kspan;

  f32x4 acc[MF][NF] = {};

  // --- staging: thread covers 4x 16B chunks (A rows trow, trow+BM/2; B same) ---
  const int trow = tid >> 2;
  const int koff = ((tid & 3) * 8) ^ (((tid >> 5) & 1) * 16);  // inverse-swizzled source k
  const unsigned short* gA0 = Ap + (size_t)(m0 + trow) * LDA + koff + koff0;
  const unsigned short* gA1 = Ap + (size_t)(m0 + BM / 2 + trow) * LDA + koff + koff0;
  const unsigned short* gB0 = Bp + (size_t)(n0 + trow) * LDB + koff + koff0;
  const unsigned short* gB1 = Bp + (size_t)(n0 + BN / 2 + trow) * LDB + koff + koff0;
  const int wave16 = (tid & ~63) * 16;   // wave-uniform LDS chunk base

  auto stage = [&](int slot, int k0) {
    char* base = lds + slot * SLOT;
    gload_lds16(gA0 + k0, base + wave16);
    gload_lds16(gA1 + k0, base + BM * 32 + wave16);
    gload_lds16(gB0 + k0, base + BM * 64 + wave16);
    gload_lds16(gB1 + k0, base + BM * 64 + BN * 32 + wave16);
  };

  // --- fragment read offsets (within slot); xor bit5 by row bit3 ---
  const int xorv = ((l >> 3) & 1) << 5;
  const int aoff = (wr * (MF * 16) + lr) * 64 + lk * 16;            // + mf*1024
  const int boff = BM * 64 + (wc * (NF * 16) + lr) * 64 + lk * 16;  // + nf*1024

  auto ldfrags = [&](int slot, bf16x8 (&pa)[MF], bf16x8 (&pb)[NF]) {
    const char* sb = lds + slot * SLOT;
    #pragma unroll
    for (int mf = 0; mf < MF; ++mf)
      pa[mf] = *(const bf16x8*)(sb + ((aoff + mf * 1024) ^ xorv));
    #pragma unroll
    for (int nf = 0; nf < NF; ++nf)
      pb[nf] = *(const bf16x8*)(sb + ((boff + nf * 1024) ^ xorv));
  };

  const int nsteps = kspan >> 5;         // even by construction
  bf16x8 fa[MF], fb[NF], ga[MF], gb[NF];

  stage(0, 0); stage(1, 32); stage(2, 64);
  asm volatile("s_waitcnt vmcnt(8)" ::: "memory");   // slot 0 landed (own wave)
  __builtin_amdgcn_s_barrier();                      // slot 0 landed (all waves)
  ldfrags(0, fa, fb);                                // prefetch step-0 frags

  auto step = [&](int s, bf16x8 (&ca)[MF], bf16x8 (&cb)[NF],
                  bf16x8 (&xa)[MF], bf16x8 (&xb2)[NF]) {
    __builtin_amdgcn_sched_barrier(0);
    if (s < nsteps - 2) asm volatile("s_waitcnt vmcnt(4)" ::: "memory");
    else                asm volatile("s_waitcnt vmcnt(0)" ::: "memory");
    __builtin_amdgcn_s_barrier();
    __builtin_amdgcn_sched_barrier(0);

    if (s + 3 < nsteps) stage((s + 3) & 3, (s + 3) << 5);  // slot (s-1)&3, read done @s-2
    if (s + 1 < nsteps) ldfrags((s + 1) & 3, xa, xb2);     // prefetch next step's frags

    __builtin_amdgcn_s_setprio(1);
    #pragma unroll
    for (int mf = 0; mf < MF; ++mf)
      #pragma unroll
      for (int nf = 0; nf < NF; ++nf)
        acc[mf][nf] = __builtin_amdgcn_mfma_f32_16x16x32_bf16(ca[mf], cb[nf], acc[mf][nf], 0, 0, 0);
    __builtin_amdgcn_s_setprio(0);
  };

  for (int s = 0; s < nsteps; s += 2) {
    step(s,     fa, fb, ga, gb);   // consume fa/fb, prefetch into ga/gb
    step(s + 1, ga, gb, fa, fb);   // consume ga/gb, prefetch into fa/fb
  }

  #pragma unroll
  for (int mf = 0; mf < MF; ++mf)
    #pragma unroll
    for (int nf = 0; nf < NF; ++nf)
      #pragma unroll
      for (int i = 0; i < 4; ++i) {
        int r = m0 + wr * (MF * 16) + mf * 16 + lk * 4 + i;
        int c = n0 + wc * (NF * 16) + nf * 16 + lr;
        float v = acc[mf][nf][i] * cscale;
        if constexpr (DOEXP)   v = __expf(v);
        if constexpr (DOSCALE) v *= rowinv[r];
        if constexpr (__is_same(OUT_T, unsigned short)) Cp[(size_t)r * LDC + c] = f2bf(v);
        else                                            Cp[(size_t)r * LDC + c] = v;
      }
}

// ------- rowinv[r] = 1 / sum(P[r][:]) ; P bf16 [4096][4096], one wave per row -------
__global__ __launch_bounds__(256) void rowsum(const unsigned short* __restrict__ P,
                                              float* __restrict__ rowinv) {
  const int wv = threadIdx.x >> 6, l = threadIdx.x & 63;
  const int r = blockIdx.x * 4 + wv;
  const unsigned short* row = P + (size_t)r * 4096;
  float sum = 0.f;
  #pragma unroll
  for (int j = 0; j < 8; ++j) {
    us8 v = ((const us8*)row)[l + j * 64];
    #pragma unroll
    for (int c = 0; c < 8; ++c) sum += bf2f(v[c]);
  }
  #pragma unroll
  for (int o = 32; o > 0; o >>= 1) sum += __shfl_xor(sum, o);
  if (l == 0) rowinv[r] = 1.f / sum;
}

// ------- out += p1 (f4 elementwise) -------
__global__ __launch_bounds__(256) void reduce_add(float* __restrict__ out,
                                                  const float* __restrict__ p1) {
  int i = blockIdx.x * 256 + threadIdx.x;
  f4 a = ((const f4*)out)[i];
  f4 b = ((const f4*)p1)[i];
  #pragma unroll
  for (int c = 0; c < 4; ++c) a[c] += b[c];
  ((f4*)out)[i] = a;
}

extern "C" void kernel_launch(void* const* d_in, const int* in_sizes, int n_in,
                              void* d_out, int out_size, void* d_ws, size_t ws_size,
                              hipStream_t stream) {
  const float* x  = (const float*)d_in[0];
  const float* Wq = (const float*)d_in[1];
  const float* Wk = (const float*)d_in[2];
  const float* Wv = (const float*)d_in[3];
  float* out = (float*)d_out;
  char* ws = (char*)d_ws;

  // ws layout (bytes):
  //   [0, 12582912)            qkv bf16 [4096][1536] (Q|K); dead after QK gemm ->
  //                            reused as PV split-K partial p1 fp32 [4096][768] (same size)
  //   [18874368, 52428800)     P bf16 [4096][4096] (unnormalized exp(scores))
  //       xb (6.3MB) and wt (3.5MB) alias this region; both dead before QK writes P
  //   [52428800, 58720256)     Vt bf16 [768][4096] (written directly by unified gemm)
  //   [58720256, 58736640)     rowinv fp32 [4096]
  unsigned short* qkv = (unsigned short*)ws;
  unsigned short* P   = (unsigned short*)(ws + 18874368);
  unsigned short* xb  = (unsigned short*)(ws + 18874368);
  unsigned short* wt  = (unsigned short*)(ws + 18874368 + 6291456);
  unsigned short* vt  = (unsigned short*)(ws + 52428800);
  float* rowinvp      = (float*)(ws + 58720256);
  float* p1           = (float*)ws;                    // aliases qkv (dead by then)

  const float qscale = 0.03608439182435161f;  // 1/sqrt(768)

  convfused<<<4800, 256, 0, stream>>>(x, Wq, Wk, Wv, xb, wt);
  // Unified projection dispatch (576 blocks, ring-4+RA, K=768):
  //   blocks [0,384):  QK-part  = x @ [Wq|Wk]  -> qkv [4096][1536]  (M=4096,N=1536)
  //   blocks [384,576): VT-part = Wv^T @ x^T   -> vt  [768][4096]   (M=768, N=4096)
  //     (V^T computed directly as a GEMM: C[d][s] = sum_k wt_v[d][k]*xb[s][k])
  gemmdp<4, 2, 2, 2, unsigned short, false, false, true><<<576, 256, 0, stream>>>(
      xb, wt, qkv, qkv, nullptr,
      wt + (size_t)1536 * 768, xb, vt,
      768, 768, 1536, 12,
      768, 768, 4096, 32,
      384, 768, 1.0f);
  // P = exp((Q @ K^T) * qscale)  (M=4096, N=4096, K=768), 256x256 -> 256 blocks, ring-4+RA
  gemmdp<8, 2, 4, 2, unsigned short, true, false, false><<<256, 512, 0, stream>>>(
      qkv, qkv + 768, P, P, nullptr, nullptr, nullptr, nullptr,
      1536, 1536, 4096, 16, 0, 0, 0, 0, 0, 768, qscale);
  // rowinv = 1 / row-sums of P
  rowsum<<<1024, 256, 0, stream>>>(P, rowinvp);
  // out = (P @ V) * rowinv (M=4096, N=768, K=4096), 128x128, split-K=2, ring-4+RA
  gemmdp<4, 2, 2, 2, float, false, true, false><<<dim3(192, 2), 256, 0, stream>>>(
      P, vt, out, p1, rowinvp, nullptr, nullptr, nullptr,
      4096, 4096, 768, 6, 0, 0, 0, 0, 0, 2048, 1.0f);
  reduce_add<<<3072, 256, 0, stream>>>(out, p1);
}